// Round 1
// baseline (20814.450 us; speedup 1.0000x reference)
//
#include <hip/hip_runtime.h>
#include <hip/hip_bf16.h>
#include <math.h>

// DARQN: conv×3 -> per-step additive attention + LSTM scan (T=2048) -> q head.
// Strategy: convs + A=vecs@W1^T batched; sequential scan via 13 persistent
// workgroups, flag-synced (2 agent-scope hops/step), all scan weights held in
// registers as MFMA B-fragments (zero per-step weight traffic).

#define T_FRAMES 2048
#define NI 49
#define HID 256
#define NA 18
#define NWG 13

typedef __bf16 v8bf __attribute__((ext_vector_type(8)));
typedef float v4f __attribute__((ext_vector_type(4)));

// ---------------- workspace layout (bytes). total needed ~252 MB ----------------
static constexpr size_t OFF_FM1   = 0;                  // fm1 [2048,32,20,20] f32 (104857600); reused for A [2048,49,256] f32
static constexpr size_t OFF_FM2   = 104857600;          // fm2 [2048,64,9,9] f32 (42467328); reused for comm block
static constexpr size_t OFF_VECS  = 147324928;          // vecs [2048,49,256] f32 (102760448)
static constexpr size_t OFF_W2B   = 250085376;          // bf16 256*256
static constexpr size_t OFF_WIHB  = OFF_W2B  + 131072;  // bf16 1024*256
static constexpr size_t OFF_WHHB  = OFF_WIHB + 524288;  // bf16 1024*256
static constexpr size_t OFF_W1T   = OFF_WHHB + 524288;  // f32 256*256 (transposed attn_w1)
// comm block aliases fm2 region (only valid after conv3 has consumed fm2):
static constexpr size_t OFF_HBUF  = OFF_FM2;                    // f32 (2049*256)
static constexpr size_t OFF_CPART = OFF_FM2 + 2098176;          // f32 (2048*13*256)
static constexpr size_t OFF_CCNT  = OFF_CPART + 27262976;       // u32 2048
static constexpr size_t OFF_HCNT  = OFF_CCNT + 8192;            // u32 2049

// ---------------- weight prep: f32 -> bf16, transpose W1 ----------------
__global__ void prep_weights(const float* __restrict__ w2, const float* __restrict__ wih,
                             const float* __restrict__ whh, const float* __restrict__ w1,
                             __bf16* w2b, __bf16* wihb, __bf16* whhb, float* w1t) {
  int idx = blockIdx.x * 256 + threadIdx.x;
  int stride = gridDim.x * 256;
  for (int i = idx; i < 65536; i += stride) w2b[i] = (__bf16)w2[i];
  for (int i = idx; i < 262144; i += stride) wihb[i] = (__bf16)wih[i];
  for (int i = idx; i < 262144; i += stride) whhb[i] = (__bf16)whh[i];
  for (int i = idx; i < 65536; i += stride) {
    int r = i >> 8, c = i & 255;
    w1t[c * 256 + r] = w1[i];
  }
}

// ---------------- conv1: [T,1,84,84] -> [T,32,20,20], k8 s4 ----------------
__global__ void conv1_k(const float* __restrict__ x, const float* __restrict__ w,
                        const float* __restrict__ b, float* __restrict__ y) {
  int idx = blockIdx.x * 256 + threadIdx.x;
  if (idx >= T_FRAMES * 32 * 20 * 20) return;
  int xx = idx % 20, yy = (idx / 20) % 20, o = (idx / 400) % 32, t = idx / 12800;
  const float* xp = x + t * 7056 + yy * 4 * 84 + xx * 4;
  const float* wp = w + o * 64;
  float acc = b[o];
  #pragma unroll
  for (int ky = 0; ky < 8; ky++)
    #pragma unroll
    for (int kx = 0; kx < 8; kx++)
      acc += xp[ky * 84 + kx] * wp[ky * 8 + kx];
  y[idx] = fmaxf(acc, 0.f);
}

// ---------------- conv2: [T,32,20,20] -> [T,64,9,9], k4 s2 ----------------
__global__ __launch_bounds__(256) void conv2_k(const float* __restrict__ fm1, const float* __restrict__ w,
                                               const float* __restrict__ b, float* __restrict__ fm2) {
  __shared__ float xs[32 * 400];  // 51.2KB
  int t = blockIdx.x, tid = threadIdx.x;
  for (int i = tid; i < 12800; i += 256) xs[i] = fm1[t * 12800 + i];
  __syncthreads();
  int o = tid >> 2, q = tid & 3;
  int p0 = q * 21, p1 = (p0 + 21 < 81) ? p0 + 21 : 81;
  int ob[21];
  #pragma unroll
  for (int i2 = 0; i2 < 21; i2++) {
    int p = p0 + i2; if (p > 80) p = 80;
    int yy = p / 9, xx2 = p - yy * 9;
    ob[i2] = yy * 40 + xx2 * 2;
  }
  float acc[21];
  #pragma unroll
  for (int i2 = 0; i2 < 21; i2++) acc[i2] = 0.f;
  for (int c = 0; c < 32; c++) {
    int cbase = c * 400;
    for (int ky = 0; ky < 4; ky++)
      for (int kx = 0; kx < 4; kx++) {
        float wgt = w[((o * 32 + c) * 4 + ky) * 4 + kx];
        int kyo = ky * 20 + kx;
        #pragma unroll
        for (int i2 = 0; i2 < 21; i2++)
          acc[i2] += wgt * xs[cbase + ob[i2] + kyo];
      }
  }
  float bo = b[o];
  #pragma unroll
  for (int i2 = 0; i2 < 21; i2++) {
    int p = p0 + i2;
    if (p < p1) fm2[t * 5184 + o * 81 + p] = fmaxf(acc[i2] + bo, 0.f);
  }
}

// ---------------- conv3: [T,64,9,9] -> vecs [T,49,256], k3 s1 ----------------
__global__ __launch_bounds__(256) void conv3_k(const float* __restrict__ fm2, const float* __restrict__ w,
                                               const float* __restrict__ b, float* __restrict__ vecs) {
  __shared__ float xs[64 * 81];     // 20.7KB
  __shared__ float ws4[256][37];    // 37.9KB (c-tile of 4, +1 pad breaks bank conflicts)
  int t = blockIdx.x, tid = threadIdx.x;
  for (int i = tid; i < 64 * 81; i += 256) xs[i] = fm2[t * 5184 + i];
  float acc[49];
  #pragma unroll
  for (int i = 0; i < 49; i++) acc[i] = 0.f;
  for (int c0 = 0; c0 < 64; c0 += 4) {
    __syncthreads();
    for (int i = tid; i < 256 * 36; i += 256) {
      int oo = i / 36, j = i - oo * 36;
      ws4[oo][j] = w[oo * 576 + c0 * 9 + j];
    }
    __syncthreads();
    for (int cc = 0; cc < 4; cc++)
      for (int ky = 0; ky < 3; ky++)
        for (int kx = 0; kx < 3; kx++) {
          float wgt = ws4[tid][cc * 9 + ky * 3 + kx];
          const float* xp = &xs[(c0 + cc) * 81 + ky * 9 + kx];
          #pragma unroll
          for (int yy = 0; yy < 7; yy++)
            #pragma unroll
            for (int xx = 0; xx < 7; xx++)
              acc[yy * 7 + xx] += wgt * xp[yy * 9 + xx];
        }
  }
  float bo = b[tid];
  for (int i = 0; i < 49; i++)
    vecs[(t * 49 + i) * 256 + tid] = fmaxf(acc[i] + bo, 0.f);
}

// ---------------- A[t,i,:] = vecs[t,i,:] @ W1^T + b1 ----------------
__global__ __launch_bounds__(256) void aprep_k(const float* __restrict__ vecs, const float* __restrict__ w1t,
                                               const float* __restrict__ b1, float* __restrict__ A) {
  __shared__ float vs[49][256];  // 50.2KB
  int t = blockIdx.x, tid = threadIdx.x;
  for (int i = tid; i < 49 * 256; i += 256) vs[i >> 8][i & 255] = vecs[t * 12544 + i];
  __syncthreads();
  float acc[49];
  #pragma unroll
  for (int i = 0; i < 49; i++) acc[i] = 0.f;
  for (int k = 0; k < 256; k++) {
    float wgt = w1t[k * 256 + tid];
    #pragma unroll
    for (int i = 0; i < 49; i++) acc[i] += vs[i][k] * wgt;
  }
  float bb = b1[tid];
  for (int i = 0; i < 49; i++) A[(t * 49 + i) * 256 + tid] = acc[i] + bb;
}

// ---------------- init comm counters (must run after conv3: aliases fm2) ----------------
__global__ void init_comm(unsigned* ccnt, unsigned* hcnt) {
  int idx = blockIdx.x * 256 + threadIdx.x;
  if (idx < T_FRAMES) ccnt[idx] = 0u;
  if (idx < T_FRAMES + 1) hcnt[idx] = 0u;
}

// ---------------- the sequential scan: 13 persistent WGs ----------------
__global__ __launch_bounds__(256, 1) void scan_k(
    const float* __restrict__ A, const float* __restrict__ vecs,
    const __bf16* __restrict__ w2b, const __bf16* __restrict__ wihb, const __bf16* __restrict__ whhb,
    const float* __restrict__ b2g, const float* __restrict__ bihg, const float* __restrict__ bhhg,
    const float* __restrict__ qw, const float* __restrict__ qb,
    float* hbuf, float* cpartg, unsigned* ccnt, unsigned* hcnt, float* out) {
  __shared__ __bf16 Ss[16][264];   // s rows, bf16, padded (+8) for MFMA a-frag reads
  __shared__ float hs[HID];
  __shared__ __bf16 hbf[HID];
  __shared__ __bf16 cxbf[HID];
  __shared__ float Wt[4][HID];     // logits -> softmax weights, in place
  __shared__ float cxp[4][HID];    // per-row ctx products
  __shared__ float b2s[HID];
  __shared__ float bsum[4][32];    // b_ih + b_hh for my gate rows
  __shared__ float gb[4][32];      // gates staging
  __shared__ float cs[32];         // my slice of cell state

  const int w = blockIdx.x;
  const int tid = threadIdx.x;
  const int lane = tid & 63;
  const int wv = tid >> 6;         // wave id 0..3
  const int quad = lane >> 4;
  const int l15 = lane & 15;
  const int r0 = 4 * w;                       // my attention rows [r0, r0+nr)
  const int nr = (w < 12) ? 4 : 1;            // 12*4 + 1 = 49
  const int d0 = 20 * w;                      // my hidden dims [d0, d0+nd)
  const int nd = (w < 12) ? 20 : 16;          // 12*20 + 16 = 256
  const int ntiles = (w < 12) ? 2 : 1;

  for (int i = tid; i < 16 * 264; i += 256) (&Ss[0][0])[i] = (__bf16)0.f;
  b2s[tid] = b2g[tid];
  hs[tid] = 0.f;
  hbf[tid] = (__bf16)0.f;
  if (tid < 128) {
    int g = tid >> 5, j = tid & 31;
    float v = 0.f;
    if (j < nd) { int row = 256 * g + d0 + j; v = bihg[row] + bhhg[row]; }
    bsum[g][j] = v;
  }
  if (tid < 32) cs[tid] = 0.f;

  // ---- register-resident MFMA B-fragments ----
  // attention: wave wv owns output col tiles nt = 4*wv+ntl; B[k][n] = W2[n][k]
  v8bf BW2[4][8];
  #pragma unroll
  for (int ntl = 0; ntl < 4; ntl++) {
    const int row = (4 * wv + ntl) * 16 + l15;
    #pragma unroll
    for (int k = 0; k < 8; k++)
      BW2[ntl][k] = *(const v8bf*)(w2b + row * 256 + k * 32 + quad * 8);
  }
  // LSTM: wave wv == gate g (i,f,g,o); rows 256*g + d0 + nt*16 + n
  v8bf BIH[2][8], BHH[2][8];
  #pragma unroll
  for (int nt = 0; nt < 2; nt++) {
    int row = 256 * wv + d0 + nt * 16 + l15;
    if (row > 256 * wv + 255) row = 256 * wv + 255;  // WG12 nt=1 guard (unused outputs)
    #pragma unroll
    for (int k = 0; k < 8; k++) {
      BIH[nt][k] = *(const v8bf*)(wihb + row * 256 + k * 32 + quad * 8);
      BHH[nt][k] = *(const v8bf*)(whhb + row * 256 + k * 32 + quad * 8);
    }
  }
  __syncthreads();

  const int prow = tid >> 6;        // which of my 4 rows this thread stages
  const int pcol = (tid & 63) * 4;  // 4 contiguous cols

  for (int t = 0; t < T_FRAMES; t++) {
    // prefetch this step's A and v rows (overlaps the h spin)
    const long ebase = ((long)t * NI + r0 + prow) * HID + pcol;  // OOB rows stay inside ws
    const float4 a4 = *(const float4*)(A + ebase);
    const float4 v4 = *(const float4*)(vecs + ebase);

    if (t > 0) {  // wait for h_t
      if (tid == 0) {
        int it = 0;
        while (__hip_atomic_load(&hcnt[t], __ATOMIC_ACQUIRE, __HIP_MEMORY_SCOPE_AGENT) < NWG) {
          __builtin_amdgcn_s_sleep(2);
          if (++it > 20000000) break;  // bounded: fail loud, not hang
        }
      }
      __syncthreads();
      float hv = __hip_atomic_load(&hbuf[t * HID + tid], __ATOMIC_RELAXED, __HIP_MEMORY_SCOPE_AGENT);
      hs[tid] = hv;
      hbf[tid] = (__bf16)hv;
      __syncthreads();
    }

    // s = tanh(A[t] + h), staged bf16 into Ss (rows >= nr remain zero)
    if (prow < nr) {
      Ss[prow][pcol + 0] = (__bf16)tanhf(a4.x + hs[pcol + 0]);
      Ss[prow][pcol + 1] = (__bf16)tanhf(a4.y + hs[pcol + 1]);
      Ss[prow][pcol + 2] = (__bf16)tanhf(a4.z + hs[pcol + 2]);
      Ss[prow][pcol + 3] = (__bf16)tanhf(a4.w + hs[pcol + 3]);
    }
    __syncthreads();

    // logits = s @ W2^T + b2 via MFMA; valid rows live in lanes 0..15
    #pragma unroll
    for (int ntl = 0; ntl < 4; ntl++) {
      v4f acc = {0.f, 0.f, 0.f, 0.f};
      #pragma unroll
      for (int k = 0; k < 8; k++) {
        const v8bf av = *(const v8bf*)&Ss[l15][k * 32 + quad * 8];
        acc = __builtin_amdgcn_mfma_f32_16x16x32_bf16(av, BW2[ntl][k], acc, 0, 0, 0);
      }
      if (lane < 16) {
        const int col = (4 * wv + ntl) * 16 + lane;
        const float bb = b2s[col];
        Wt[0][col] = acc[0] + bb;
        Wt[1][col] = acc[1] + bb;
        Wt[2][col] = acc[2] + bb;
        Wt[3][col] = acc[3] + bb;
      }
    }
    __syncthreads();

    // softmax over the 256 cols, wave i -> row i
    if (wv < nr) {
      float x0 = Wt[wv][lane], x1 = Wt[wv][lane + 64], x2 = Wt[wv][lane + 128], x3 = Wt[wv][lane + 192];
      float m = fmaxf(fmaxf(x0, x1), fmaxf(x2, x3));
      #pragma unroll
      for (int off = 32; off; off >>= 1) m = fmaxf(m, __shfl_xor(m, off, 64));
      float e0 = __expf(x0 - m), e1 = __expf(x1 - m), e2 = __expf(x2 - m), e3 = __expf(x3 - m);
      float sm = e0 + e1 + e2 + e3;
      #pragma unroll
      for (int off = 32; off; off >>= 1) sm += __shfl_xor(sm, off, 64);
      float inv = 1.f / sm;
      Wt[wv][lane] = e0 * inv; Wt[wv][lane + 64] = e1 * inv;
      Wt[wv][lane + 128] = e2 * inv; Wt[wv][lane + 192] = e3 * inv;
    }
    __syncthreads();

    // ctx partial: sum_i w[i,ch]*v[i,ch] over my rows
    if (prow < nr) {
      cxp[prow][pcol + 0] = Wt[prow][pcol + 0] * v4.x;
      cxp[prow][pcol + 1] = Wt[prow][pcol + 1] * v4.y;
      cxp[prow][pcol + 2] = Wt[prow][pcol + 2] * v4.z;
      cxp[prow][pcol + 3] = Wt[prow][pcol + 3] * v4.w;
    }
    __syncthreads();
    float cp = 0.f;
    for (int i = 0; i < nr; i++) cp += cxp[i][tid];
    __hip_atomic_store(&cpartg[((long)t * NWG + w) * HID + tid], cp, __ATOMIC_RELAXED, __HIP_MEMORY_SCOPE_AGENT);
    __syncthreads();
    if (tid == 0) {
      __threadfence();
      __hip_atomic_fetch_add(&ccnt[t], 1u, __ATOMIC_RELEASE, __HIP_MEMORY_SCOPE_AGENT);
      int it = 0;
      while (__hip_atomic_load(&ccnt[t], __ATOMIC_ACQUIRE, __HIP_MEMORY_SCOPE_AGENT) < NWG) {
        __builtin_amdgcn_s_sleep(2);
        if (++it > 20000000) break;
      }
    }
    __syncthreads();

    // gather full ctx
    {
      float cx = 0.f;
      #pragma unroll
      for (int p = 0; p < NWG; p++)
        cx += __hip_atomic_load(&cpartg[((long)t * NWG + p) * HID + tid], __ATOMIC_RELAXED, __HIP_MEMORY_SCOPE_AGENT);
      cxbf[tid] = (__bf16)cx;
    }
    __syncthreads();

    // gates = ctx@W_ih^T + h@W_hh^T + biases, via M=1 MFMA (only m=0 lanes carry A)
    #pragma unroll
    for (int nt = 0; nt < 2; nt++) {
      if (nt < ntiles) {
        v4f acc = {0.f, 0.f, 0.f, 0.f};
        #pragma unroll
        for (int k = 0; k < 8; k++) {
          v8bf az;
          #pragma unroll
          for (int z = 0; z < 8; z++) az[z] = (__bf16)0.f;
          v8bf actx = az, ahh = az;
          if (l15 == 0) {
            actx = *(const v8bf*)&cxbf[k * 32 + quad * 8];
            ahh  = *(const v8bf*)&hbf[k * 32 + quad * 8];
          }
          acc = __builtin_amdgcn_mfma_f32_16x16x32_bf16(actx, BIH[nt][k], acc, 0, 0, 0);
          acc = __builtin_amdgcn_mfma_f32_16x16x32_bf16(ahh,  BHH[nt][k], acc, 0, 0, 0);
        }
        if (lane < 16) {
          const int j = nt * 16 + lane;
          gb[wv][j] = acc[0] + bsum[wv][j];
        }
      }
    }
    __syncthreads();

    // cell update for my nd dims; publish h part
    if (tid < nd) {
      float gi = gb[0][tid], gf = gb[1][tid], gg = gb[2][tid], go = gb[3][tid];
      float si = 1.f / (1.f + __expf(-gi));
      float sf = 1.f / (1.f + __expf(-gf));
      float so = 1.f / (1.f + __expf(-go));
      float cc = sf * cs[tid] + si * tanhf(gg);
      cs[tid] = cc;
      float hn = so * tanhf(cc);
      __hip_atomic_store(&hbuf[(t + 1) * HID + d0 + tid], hn, __ATOMIC_RELAXED, __HIP_MEMORY_SCOPE_AGENT);
    }
    __syncthreads();
    if (tid == 0) {
      __threadfence();
      __hip_atomic_fetch_add(&hcnt[t + 1], 1u, __ATOMIC_RELEASE, __HIP_MEMORY_SCOPE_AGENT);
    }
  }

  // q = h_T @ q_w^T + q_b
  if (w == 0) {
    if (tid == 0) {
      int it = 0;
      while (__hip_atomic_load(&hcnt[T_FRAMES], __ATOMIC_ACQUIRE, __HIP_MEMORY_SCOPE_AGENT) < NWG) {
        __builtin_amdgcn_s_sleep(2);
        if (++it > 20000000) break;
      }
    }
    __syncthreads();
    hs[tid] = __hip_atomic_load(&hbuf[T_FRAMES * HID + tid], __ATOMIC_RELAXED, __HIP_MEMORY_SCOPE_AGENT);
    __syncthreads();
    if (tid < NA) {
      float acc = qb[tid];
      for (int k = 0; k < HID; k++) acc += hs[k] * qw[tid * HID + k];
      out[tid] = acc;
    }
  }
}

extern "C" void kernel_launch(void* const* d_in, const int* in_sizes, int n_in,
                              void* d_out, int out_size, void* d_ws, size_t ws_size,
                              hipStream_t stream) {
  const float* frames = (const float*)d_in[0];
  const float* c1w = (const float*)d_in[1];
  const float* c1b = (const float*)d_in[2];
  const float* c2w = (const float*)d_in[3];
  const float* c2b = (const float*)d_in[4];
  const float* c3w = (const float*)d_in[5];
  const float* c3b = (const float*)d_in[6];
  const float* aw1 = (const float*)d_in[7];
  const float* ab1 = (const float*)d_in[8];
  const float* aw2 = (const float*)d_in[9];
  const float* ab2 = (const float*)d_in[10];
  const float* wih = (const float*)d_in[11];
  const float* whh = (const float*)d_in[12];
  const float* bih = (const float*)d_in[13];
  const float* bhh = (const float*)d_in[14];
  const float* qw  = (const float*)d_in[15];
  const float* qb  = (const float*)d_in[16];

  char* ws = (char*)d_ws;
  float*  fm1   = (float*)(ws + OFF_FM1);
  float*  A     = (float*)(ws + OFF_FM1);   // alias: fm1 dead after conv2
  float*  fm2   = (float*)(ws + OFF_FM2);
  float*  vecs  = (float*)(ws + OFF_VECS);
  __bf16* w2b   = (__bf16*)(ws + OFF_W2B);
  __bf16* wihb  = (__bf16*)(ws + OFF_WIHB);
  __bf16* whhb  = (__bf16*)(ws + OFF_WHHB);
  float*  w1t   = (float*)(ws + OFF_W1T);
  float*  hbuf  = (float*)(ws + OFF_HBUF);   // alias: fm2 dead after conv3
  float*  cpart = (float*)(ws + OFF_CPART);
  unsigned* ccnt = (unsigned*)(ws + OFF_CCNT);
  unsigned* hcnt = (unsigned*)(ws + OFF_HCNT);

  prep_weights<<<256, 256, 0, stream>>>(aw2, wih, whh, aw1, w2b, wihb, whhb, w1t);
  conv1_k<<<102400, 256, 0, stream>>>(frames, c1w, c1b, fm1);
  conv2_k<<<T_FRAMES, 256, 0, stream>>>(fm1, c2w, c2b, fm2);
  conv3_k<<<T_FRAMES, 256, 0, stream>>>(fm2, c3w, c3b, vecs);
  aprep_k<<<T_FRAMES, 256, 0, stream>>>(vecs, w1t, ab1, A);
  init_comm<<<9, 256, 0, stream>>>(ccnt, hcnt);  // after conv3: comm aliases fm2
  scan_k<<<NWG, 256, 0, stream>>>(A, vecs, w2b, wihb, whhb, ab2, bih, bhh, qw, qb,
                                  hbuf, cpart, ccnt, hcnt, (float*)d_out);
}

// Round 2
// 15998.734 us; speedup vs baseline: 1.3010x; 1.3010x over previous
//
#include <hip/hip_runtime.h>
#include <hip/hip_bf16.h>
#include <math.h>

// DARQN: conv×3 -> per-step additive attention + LSTM scan (T=2048) -> q head.
// R2: scan rebuilt around per-WG flag lines (no counter RMWs, no threadfence),
// 8 persistent WGs, single-slot comm buffers, bf16 ctx-partials consumed
// directly as MFMA P-matrix rows (row-sum reduce), h@Whh chain overlapped
// with the ctx wait. All scan weights register-resident as MFMA B-frags.

#define T_FRAMES 2048
#define NI 49
#define HID 256
#define NA 18
#define NWG 8

typedef __bf16 v8bf __attribute__((ext_vector_type(8)));
typedef float v4f __attribute__((ext_vector_type(4)));

// ---------------- workspace layout (bytes) ----------------
static constexpr size_t OFF_FM1   = 0;                  // fm1 [2048,32,20,20] f32; reused for A [2048,49,256] f32
static constexpr size_t OFF_FM2   = 104857600;          // fm2 [2048,64,9,9] f32; reused for comm block
static constexpr size_t OFF_VECS  = 147324928;          // vecs [2048,49,256] f32
static constexpr size_t OFF_W2B   = 250085376;          // bf16 256*256
static constexpr size_t OFF_WIHB  = OFF_W2B  + 131072;  // bf16 1024*256
static constexpr size_t OFF_WHHB  = OFF_WIHB + 524288;  // bf16 1024*256
static constexpr size_t OFF_W1T   = OFF_WHHB + 524288;  // f32 256*256
// comm block aliases fm2 region (valid after conv3 consumed fm2):
static constexpr size_t OFF_HBUF  = OFF_FM2;            // f32[256]   single slot
static constexpr size_t OFF_CPUB  = OFF_FM2 + 1024;     // uint[8*256] (bf16 pairs), single slot per WG
static constexpr size_t OFF_FLH   = OFF_FM2 + 9216;     // u32[8*32]
static constexpr size_t OFF_FLC   = OFF_FM2 + 10240;    // u32[8*32]

// ---------------- weight prep ----------------
__global__ void prep_weights(const float* __restrict__ w2, const float* __restrict__ wih,
                             const float* __restrict__ whh, const float* __restrict__ w1,
                             __bf16* w2b, __bf16* wihb, __bf16* whhb, float* w1t) {
  int idx = blockIdx.x * 256 + threadIdx.x;
  int stride = gridDim.x * 256;
  for (int i = idx; i < 65536; i += stride) w2b[i] = (__bf16)w2[i];
  for (int i = idx; i < 262144; i += stride) wihb[i] = (__bf16)wih[i];
  for (int i = idx; i < 262144; i += stride) whhb[i] = (__bf16)whh[i];
  for (int i = idx; i < 65536; i += stride) {
    int r = i >> 8, c = i & 255;
    w1t[c * 256 + r] = w1[i];
  }
}

// ---------------- conv1: [T,1,84,84] -> [T,32,20,20], k8 s4 ----------------
__global__ void conv1_k(const float* __restrict__ x, const float* __restrict__ w,
                        const float* __restrict__ b, float* __restrict__ y) {
  int idx = blockIdx.x * 256 + threadIdx.x;
  if (idx >= T_FRAMES * 32 * 20 * 20) return;
  int xx = idx % 20, yy = (idx / 20) % 20, o = (idx / 400) % 32, t = idx / 12800;
  const float* xp = x + t * 7056 + yy * 4 * 84 + xx * 4;
  const float* wp = w + o * 64;
  float acc = b[o];
  #pragma unroll
  for (int ky = 0; ky < 8; ky++)
    #pragma unroll
    for (int kx = 0; kx < 8; kx++)
      acc += xp[ky * 84 + kx] * wp[ky * 8 + kx];
  y[idx] = fmaxf(acc, 0.f);
}

// ---------------- conv2: [T,32,20,20] -> [T,64,9,9], k4 s2 ----------------
__global__ __launch_bounds__(256) void conv2_k(const float* __restrict__ fm1, const float* __restrict__ w,
                                               const float* __restrict__ b, float* __restrict__ fm2) {
  __shared__ float xs[32 * 400];
  int t = blockIdx.x, tid = threadIdx.x;
  for (int i = tid; i < 12800; i += 256) xs[i] = fm1[t * 12800 + i];
  __syncthreads();
  int o = tid >> 2, q = tid & 3;
  int p0 = q * 21, p1 = (p0 + 21 < 81) ? p0 + 21 : 81;
  int ob[21];
  #pragma unroll
  for (int i2 = 0; i2 < 21; i2++) {
    int p = p0 + i2; if (p > 80) p = 80;
    int yy = p / 9, xx2 = p - yy * 9;
    ob[i2] = yy * 40 + xx2 * 2;
  }
  float acc[21];
  #pragma unroll
  for (int i2 = 0; i2 < 21; i2++) acc[i2] = 0.f;
  for (int c = 0; c < 32; c++) {
    int cbase = c * 400;
    for (int ky = 0; ky < 4; ky++)
      for (int kx = 0; kx < 4; kx++) {
        float wgt = w[((o * 32 + c) * 4 + ky) * 4 + kx];
        int kyo = ky * 20 + kx;
        #pragma unroll
        for (int i2 = 0; i2 < 21; i2++)
          acc[i2] += wgt * xs[cbase + ob[i2] + kyo];
      }
  }
  float bo = b[o];
  #pragma unroll
  for (int i2 = 0; i2 < 21; i2++) {
    int p = p0 + i2;
    if (p < p1) fm2[t * 5184 + o * 81 + p] = fmaxf(acc[i2] + bo, 0.f);
  }
}

// ---------------- conv3: [T,64,9,9] -> vecs [T,49,256], k3 s1 ----------------
__global__ __launch_bounds__(256) void conv3_k(const float* __restrict__ fm2, const float* __restrict__ w,
                                               const float* __restrict__ b, float* __restrict__ vecs) {
  __shared__ float xs[64 * 81];
  __shared__ float ws4[256][37];
  int t = blockIdx.x, tid = threadIdx.x;
  for (int i = tid; i < 64 * 81; i += 256) xs[i] = fm2[t * 5184 + i];
  float acc[49];
  #pragma unroll
  for (int i = 0; i < 49; i++) acc[i] = 0.f;
  for (int c0 = 0; c0 < 64; c0 += 4) {
    __syncthreads();
    for (int i = tid; i < 256 * 36; i += 256) {
      int oo = i / 36, j = i - oo * 36;
      ws4[oo][j] = w[oo * 576 + c0 * 9 + j];
    }
    __syncthreads();
    for (int cc = 0; cc < 4; cc++)
      for (int ky = 0; ky < 3; ky++)
        for (int kx = 0; kx < 3; kx++) {
          float wgt = ws4[tid][cc * 9 + ky * 3 + kx];
          const float* xp = &xs[(c0 + cc) * 81 + ky * 9 + kx];
          #pragma unroll
          for (int yy = 0; yy < 7; yy++)
            #pragma unroll
            for (int xx = 0; xx < 7; xx++)
              acc[yy * 7 + xx] += wgt * xp[yy * 9 + xx];
        }
  }
  float bo = b[tid];
  for (int i = 0; i < 49; i++)
    vecs[(t * 49 + i) * 256 + tid] = fmaxf(acc[i] + bo, 0.f);
}

// ---------------- A[t,i,:] = vecs[t,i,:] @ W1^T + b1 ----------------
__global__ __launch_bounds__(256) void aprep_k(const float* __restrict__ vecs, const float* __restrict__ w1t,
                                               const float* __restrict__ b1, float* __restrict__ A) {
  __shared__ float vs[49][256];
  int t = blockIdx.x, tid = threadIdx.x;
  for (int i = tid; i < 49 * 256; i += 256) vs[i >> 8][i & 255] = vecs[t * 12544 + i];
  __syncthreads();
  float acc[49];
  #pragma unroll
  for (int i = 0; i < 49; i++) acc[i] = 0.f;
  for (int k = 0; k < 256; k++) {
    float wgt = w1t[k * 256 + tid];
    #pragma unroll
    for (int i = 0; i < 49; i++) acc[i] += vs[i][k] * wgt;
  }
  float bb = b1[tid];
  for (int i = 0; i < 49; i++) A[(t * 49 + i) * 256 + tid] = acc[i] + bb;
}

// ---------------- init comm flags (after conv3: aliases fm2) ----------------
__global__ void init_comm(unsigned* flh, unsigned* flc) {
  int idx = blockIdx.x * 512 + threadIdx.x;
  if (idx < NWG * 32) { flh[idx] = 0u; flc[idx] = 0u; }
}

__device__ __forceinline__ float tanh_fast(float x) {
  float e = __expf(2.f * x);
  return 1.f - 2.f / (e + 1.f);
}

// ---------------- sequential scan: 8 persistent WGs, flag-synced ----------------
__global__ __launch_bounds__(256, 1) void scan_k(
    const float* __restrict__ A, const float* __restrict__ vecs,
    const __bf16* __restrict__ w2b, const __bf16* __restrict__ wihb, const __bf16* __restrict__ whhb,
    const float* __restrict__ b2g, const float* __restrict__ bihg, const float* __restrict__ bhhg,
    const float* __restrict__ qw, const float* __restrict__ qb,
    float* hbuf, unsigned* cpub, unsigned* flh, unsigned* flc, float* out) {
  __shared__ __bf16 Ss[16][264];   // row byte-stride 528 (16B-aligned)
  __shared__ float hs[HID];
  __shared__ __bf16 hbf[HID];
  __shared__ float Wt[8][HID];     // logits / softmax rows
  __shared__ float cxp[8][HID];    // per-row ctx products
  __shared__ float b2s[HID];
  __shared__ float gb[4][32];

  const int w = blockIdx.x;
  const int tid = threadIdx.x;
  const int lane = tid & 63;
  const int wv = tid >> 6;          // wave 0..3 (= LSTM gate id)
  const int quad = lane >> 4;
  const int l15 = lane & 15;
  const int r0 = 6 * w;                       // attention rows [r0, r0+nr)
  const int nr = (w < 7) ? 6 : 7;             // 7*6 + 7 = 49
  const int prow = tid >> 5;        // 0..7: staging row
  const int pcol = (tid & 31) * 8;  // 8 contiguous cols

  for (int i = tid; i < 16 * 264; i += 256) (&Ss[0][0])[i] = (__bf16)0.f;
  for (int i = tid; i < 8 * HID; i += 256) (&cxp[0][0])[i] = 0.f;
  b2s[tid] = b2g[tid];
  hs[tid] = 0.f;
  hbf[tid] = (__bf16)0.f;
  float cbias[4];
  if (tid < 32) {
    #pragma unroll
    for (int g = 0; g < 4; g++) {
      int row = 256 * g + 32 * w + tid;
      cbias[g] = bihg[row] + bhhg[row];
    }
  }
  float creg = 0.f;  // cell state, tid<32 owns dim 32*w+tid

  // ---- register-resident MFMA B-fragments ----
  v8bf BW2[4][8];  // attention: wave wv owns logit cols wv*64 + ntl*16 + l15
  #pragma unroll
  for (int ntl = 0; ntl < 4; ntl++) {
    const int row = wv * 64 + ntl * 16 + l15;
    #pragma unroll
    for (int k = 0; k < 8; k++)
      BW2[ntl][k] = *(const v8bf*)(w2b + row * 256 + k * 32 + quad * 8);
  }
  v8bf BIH[2][8], BHH[2][8];  // LSTM: gate wv, dims 32*w + nt*16 + l15
  #pragma unroll
  for (int nt = 0; nt < 2; nt++) {
    const int row = 256 * wv + 32 * w + nt * 16 + l15;
    #pragma unroll
    for (int k = 0; k < 8; k++) {
      BIH[nt][k] = *(const v8bf*)(wihb + row * 256 + k * 32 + quad * 8);
      BHH[nt][k] = *(const v8bf*)(whhb + row * 256 + k * 32 + quad * 8);
    }
  }
  __syncthreads();

  for (int t = 0; t < T_FRAMES; t++) {
    // issue this step's A/vecs loads (fly during the h-flag wait)
    int rr = r0 + prow; if (rr > 48) rr = 48;
    const float* Ap = A + ((long)t * NI + rr) * HID + pcol;
    const float* Vp = vecs + ((long)t * NI + rr) * HID + pcol;
    const float4 a40 = *(const float4*)(Ap);
    const float4 a41 = *(const float4*)(Ap + 4);
    const float4 v40 = *(const float4*)(Vp);
    const float4 v41 = *(const float4*)(Vp + 4);

    if (t > 0) {  // wait for h_t (flag value t), then load it
      if (wv == 0) {
        const unsigned tgt = (unsigned)t;
        int guard = 0;
        while (true) {
          unsigned fv = (lane < NWG)
              ? __hip_atomic_load(&flh[lane * 32], __ATOMIC_RELAXED, __HIP_MEMORY_SCOPE_AGENT)
              : tgt;
          if (__all(fv >= tgt) || ++guard > 5000000) break;
          __builtin_amdgcn_s_sleep(1);
        }
      }
      __syncthreads();  // B0
      float hv = __hip_atomic_load(&hbuf[tid], __ATOMIC_RELAXED, __HIP_MEMORY_SCOPE_AGENT);
      hs[tid] = hv;
      hbf[tid] = (__bf16)hv;
      __syncthreads();  // B1
    }

    // stage s = tanh(A + h) as bf16 (rows >= nr stay zero)
    if (prow < nr) {
      const float* hp = &hs[pcol];
      v8bf sv;
      sv[0] = (__bf16)tanh_fast(a40.x + hp[0]);
      sv[1] = (__bf16)tanh_fast(a40.y + hp[1]);
      sv[2] = (__bf16)tanh_fast(a40.z + hp[2]);
      sv[3] = (__bf16)tanh_fast(a40.w + hp[3]);
      sv[4] = (__bf16)tanh_fast(a41.x + hp[4]);
      sv[5] = (__bf16)tanh_fast(a41.y + hp[5]);
      sv[6] = (__bf16)tanh_fast(a41.z + hp[6]);
      sv[7] = (__bf16)tanh_fast(a41.w + hp[7]);
      *(v8bf*)&Ss[prow][pcol] = sv;
    }
    __syncthreads();  // B2

    // logits = s @ W2^T + b2 (rows 0..7 valid)
    v4f acc[4];
    #pragma unroll
    for (int ntl = 0; ntl < 4; ntl++) acc[ntl] = (v4f){0.f, 0.f, 0.f, 0.f};
    #pragma unroll
    for (int k = 0; k < 8; k++) {
      const v8bf av = *(const v8bf*)&Ss[l15][k * 32 + quad * 8];
      #pragma unroll
      for (int ntl = 0; ntl < 4; ntl++)
        acc[ntl] = __builtin_amdgcn_mfma_f32_16x16x32_bf16(av, BW2[ntl][k], acc[ntl], 0, 0, 0);
    }
    if (quad < 2) {
      #pragma unroll
      for (int ntl = 0; ntl < 4; ntl++) {
        const int col = wv * 64 + ntl * 16 + l15;
        const float bb = b2s[col];
        #pragma unroll
        for (int reg = 0; reg < 4; reg++)
          Wt[quad * 4 + reg][col] = acc[ntl][reg] + bb;
      }
    }
    __syncthreads();  // B3

    // softmax (row = prow, 8 cols each, reduce across the 32-lane row group)
    // + ctx products into cxp (invalid rows stay zero)
    if (prow < nr) {
      float x[8];
      *(float4*)&x[0] = *(const float4*)&Wt[prow][pcol];
      *(float4*)&x[4] = *(const float4*)&Wt[prow][pcol + 4];
      float m = x[0];
      #pragma unroll
      for (int i = 1; i < 8; i++) m = fmaxf(m, x[i]);
      #pragma unroll
      for (int off = 16; off; off >>= 1) m = fmaxf(m, __shfl_xor(m, off, 64));
      float e[8], sm = 0.f;
      #pragma unroll
      for (int i = 0; i < 8; i++) { e[i] = __expf(x[i] - m); sm += e[i]; }
      #pragma unroll
      for (int off = 16; off; off >>= 1) sm += __shfl_xor(sm, off, 64);
      const float inv = 1.f / sm;
      cxp[prow][pcol + 0] = e[0] * inv * v40.x;
      cxp[prow][pcol + 1] = e[1] * inv * v40.y;
      cxp[prow][pcol + 2] = e[2] * inv * v40.z;
      cxp[prow][pcol + 3] = e[3] * inv * v40.w;
      cxp[prow][pcol + 4] = e[4] * inv * v41.x;
      cxp[prow][pcol + 5] = e[5] * inv * v41.y;
      cxp[prow][pcol + 6] = e[6] * inv * v41.z;
      cxp[prow][pcol + 7] = e[7] * inv * v41.w;
    }
    __syncthreads();  // B5

    // channel sum of my WG's rows -> bf16 pack -> publish (single slot)
    float cp = 0.f;
    #pragma unroll
    for (int r = 0; r < 8; r++) cp += cxp[r][tid];
    float cpo = __shfl_xor(cp, 1, 64);
    if ((tid & 1) == 0) {
      union { __bf16 b; unsigned short s; } lo, hi;
      lo.b = (__bf16)cp; hi.b = (__bf16)cpo;
      unsigned u = ((unsigned)hi.s << 16) | (unsigned)lo.s;
      __hip_atomic_store(&cpub[w * 256 + (tid >> 1)], u, __ATOMIC_RELAXED, __HIP_MEMORY_SCOPE_AGENT);
    }
    __syncthreads();  // B6 (drains the publishes)
    if (tid == 0)
      __hip_atomic_store(&flc[w * 32], (unsigned)(t + 1), __ATOMIC_RELEASE, __HIP_MEMORY_SCOPE_AGENT);

    // h @ Whh^T chain first (h known since step top) — overlaps the ctx wait
    v4f gacc[2];
    gacc[0] = (v4f){0.f, 0.f, 0.f, 0.f};
    gacc[1] = (v4f){0.f, 0.f, 0.f, 0.f};
    #pragma unroll
    for (int k = 0; k < 8; k++) {
      v8bf hf;
      #pragma unroll
      for (int z = 0; z < 8; z++) hf[z] = (__bf16)0.f;
      if (l15 == 0) hf = *(const v8bf*)&hbf[k * 32 + quad * 8];
      gacc[0] = __builtin_amdgcn_mfma_f32_16x16x32_bf16(hf, BHH[0][k], gacc[0], 0, 0, 0);
      gacc[1] = __builtin_amdgcn_mfma_f32_16x16x32_bf16(hf, BHH[1][k], gacc[1], 0, 0, 0);
    }

    // wait for all ctx partials (every wave polls; no barrier needed after)
    {
      const unsigned tgt = (unsigned)(t + 1);
      int guard = 0;
      while (true) {
        unsigned fv = (lane < NWG)
            ? __hip_atomic_load(&flc[lane * 32], __ATOMIC_RELAXED, __HIP_MEMORY_SCOPE_AGENT)
            : tgt;
        if (__all(fv >= tgt) || ++guard > 5000000) break;
        __builtin_amdgcn_s_sleep(1);
      }
    }

    // gather P rows (bf16 ctx partials) directly as MFMA A-frags; accumulate
    #pragma unroll
    for (int k = 0; k < 8; k++) {
      union { unsigned long long u[2]; v8bf v; } pf;
      pf.u[0] = 0ull; pf.u[1] = 0ull;
      if (l15 < NWG) {
        const unsigned long long* src =
            (const unsigned long long*)(cpub + l15 * 256) + (k * 8 + quad * 2);
        pf.u[0] = __hip_atomic_load(src, __ATOMIC_RELAXED, __HIP_MEMORY_SCOPE_AGENT);
        pf.u[1] = __hip_atomic_load(src + 1, __ATOMIC_RELAXED, __HIP_MEMORY_SCOPE_AGENT);
      }
      gacc[0] = __builtin_amdgcn_mfma_f32_16x16x32_bf16(pf.v, BIH[0][k], gacc[0], 0, 0, 0);
      gacc[1] = __builtin_amdgcn_mfma_f32_16x16x32_bf16(pf.v, BIH[1][k], gacc[1], 0, 0, 0);
    }
    // reduce over P rows (D rows = quad*4+reg) -> per-col gate pre-activation
    #pragma unroll
    for (int nt = 0; nt < 2; nt++) {
      float tot = gacc[nt][0] + gacc[nt][1] + gacc[nt][2] + gacc[nt][3];
      tot += __shfl_xor(tot, 16, 64);
      tot += __shfl_xor(tot, 32, 64);
      if (lane < 16) gb[wv][nt * 16 + lane] = tot;
    }
    __syncthreads();  // B7

    // cell update for my 32 dims; publish h slice
    if (tid < 32) {
      float gi = gb[0][tid] + cbias[0];
      float gf = gb[1][tid] + cbias[1];
      float gg = gb[2][tid] + cbias[2];
      float go = gb[3][tid] + cbias[3];
      float si = 1.f / (1.f + __expf(-gi));
      float sf = 1.f / (1.f + __expf(-gf));
      float so = 1.f / (1.f + __expf(-go));
      creg = sf * creg + si * tanh_fast(gg);
      float hn = so * tanh_fast(creg);
      __hip_atomic_store(&hbuf[32 * w + tid], hn, __ATOMIC_RELAXED, __HIP_MEMORY_SCOPE_AGENT);
    }
    __syncthreads();  // B8 (drains h stores)
    if (tid == 0)
      __hip_atomic_store(&flh[w * 32], (unsigned)(t + 1), __ATOMIC_RELEASE, __HIP_MEMORY_SCOPE_AGENT);
  }

  // q = h_T @ q_w^T + q_b
  if (w == 0) {
    if (wv == 0) {
      const unsigned tgt = (unsigned)T_FRAMES;
      int guard = 0;
      while (true) {
        unsigned fv = (lane < NWG)
            ? __hip_atomic_load(&flh[lane * 32], __ATOMIC_RELAXED, __HIP_MEMORY_SCOPE_AGENT)
            : tgt;
        if (__all(fv >= tgt) || ++guard > 5000000) break;
        __builtin_amdgcn_s_sleep(1);
      }
    }
    __syncthreads();
    hs[tid] = __hip_atomic_load(&hbuf[tid], __ATOMIC_RELAXED, __HIP_MEMORY_SCOPE_AGENT);
    __syncthreads();
    if (tid < NA) {
      float acc = qb[tid];
      for (int k = 0; k < HID; k++) acc += hs[k] * qw[tid * HID + k];
      out[tid] = acc;
    }
  }
}

extern "C" void kernel_launch(void* const* d_in, const int* in_sizes, int n_in,
                              void* d_out, int out_size, void* d_ws, size_t ws_size,
                              hipStream_t stream) {
  const float* frames = (const float*)d_in[0];
  const float* c1w = (const float*)d_in[1];
  const float* c1b = (const float*)d_in[2];
  const float* c2w = (const float*)d_in[3];
  const float* c2b = (const float*)d_in[4];
  const float* c3w = (const float*)d_in[5];
  const float* c3b = (const float*)d_in[6];
  const float* aw1 = (const float*)d_in[7];
  const float* ab1 = (const float*)d_in[8];
  const float* aw2 = (const float*)d_in[9];
  const float* ab2 = (const float*)d_in[10];
  const float* wih = (const float*)d_in[11];
  const float* whh = (const float*)d_in[12];
  const float* bih = (const float*)d_in[13];
  const float* bhh = (const float*)d_in[14];
  const float* qw  = (const float*)d_in[15];
  const float* qb  = (const float*)d_in[16];

  char* ws = (char*)d_ws;
  float*  fm1   = (float*)(ws + OFF_FM1);
  float*  A     = (float*)(ws + OFF_FM1);   // alias: fm1 dead after conv2
  float*  fm2   = (float*)(ws + OFF_FM2);
  float*  vecs  = (float*)(ws + OFF_VECS);
  __bf16* w2b   = (__bf16*)(ws + OFF_W2B);
  __bf16* wihb  = (__bf16*)(ws + OFF_WIHB);
  __bf16* whhb  = (__bf16*)(ws + OFF_WHHB);
  float*  w1t   = (float*)(ws + OFF_W1T);
  float*    hbuf = (float*)(ws + OFF_HBUF);   // aliases fm2 (dead after conv3)
  unsigned* cpub = (unsigned*)(ws + OFF_CPUB);
  unsigned* flh  = (unsigned*)(ws + OFF_FLH);
  unsigned* flc  = (unsigned*)(ws + OFF_FLC);

  prep_weights<<<256, 256, 0, stream>>>(aw2, wih, whh, aw1, w2b, wihb, whhb, w1t);
  conv1_k<<<102400, 256, 0, stream>>>(frames, c1w, c1b, fm1);
  conv2_k<<<T_FRAMES, 256, 0, stream>>>(fm1, c2w, c2b, fm2);
  conv3_k<<<T_FRAMES, 256, 0, stream>>>(fm2, c3w, c3b, vecs);
  aprep_k<<<T_FRAMES, 256, 0, stream>>>(vecs, w1t, ab1, A);
  init_comm<<<1, 512, 0, stream>>>(flh, flc);  // after conv3: comm aliases fm2
  scan_k<<<NWG, 256, 0, stream>>>(A, vecs, w2b, wihb, whhb, ab2, bih, bhh, qw, qb,
                                  hbuf, cpub, flh, flc, (float*)d_out);
}